// Round 2
// baseline (1128.558 us; speedup 1.0000x reference)
//
#include <hip/hip_runtime.h>
#include <hip/hip_bf16.h>

#define N_NODES 200000
#define N_EDGES 640000
#define D_NODE 128
#define D_EDGE 32
#define HIDDEN 128

using bf16x8  = __attribute__((ext_vector_type(8))) short;
using f32x4   = __attribute__((ext_vector_type(4))) float;
using short4v = __attribute__((ext_vector_type(4))) short;

__device__ __forceinline__ short f2b(float f) {
  return __builtin_bit_cast(short, __float2bfloat16(f));
}
__device__ __forceinline__ float b2f(short s) {
  unsigned u = ((unsigned)(unsigned short)s) << 16;
  return __builtin_bit_cast(float, u);
}

// ===========================================================================
// CSR build: hist -> scan(3) -> place
// ===========================================================================
__global__ __launch_bounds__(256) void k_hist(const int* __restrict__ ei,
                                              int* cnt, int* slot) {
  const int e = blockIdx.x * 256 + threadIdx.x;
  if (e < N_EDGES) slot[e] = atomicAdd(&cnt[ei[N_EDGES + e]], 1);
}

#define SCAN_NB 196  // ceil(200000/1024)

__global__ __launch_bounds__(256) void k_scan_a(const int* __restrict__ cnt,
                                                int* bsum) {
  __shared__ int sh[256];
  const int b = blockIdx.x, t = threadIdx.x;
  const int base = b * 1024 + t * 4;
  int s = 0;
  #pragma unroll
  for (int k = 0; k < 4; ++k) {
    const int idx = base + k;
    s += (idx < N_NODES) ? cnt[idx] : 0;
  }
  sh[t] = s; __syncthreads();
  for (int o = 128; o > 0; o >>= 1) {
    if (t < o) sh[t] += sh[t + o];
    __syncthreads();
  }
  if (t == 0) bsum[b] = sh[0];
}

__global__ __launch_bounds__(256) void k_scan_b(const int* __restrict__ bsum,
                                                int* bpre) {
  __shared__ int sh[256];
  const int t = threadIdx.x;
  const int v0 = (t < SCAN_NB) ? bsum[t] : 0;
  sh[t] = v0; __syncthreads();
  for (int o = 1; o < 256; o <<= 1) {
    const int tv = (t >= o) ? sh[t - o] : 0;
    __syncthreads();
    sh[t] += tv;
    __syncthreads();
  }
  bpre[t] = sh[t] - v0;  // exclusive
}

__global__ __launch_bounds__(256) void k_scan_c(const int* __restrict__ cnt,
                                                const int* __restrict__ bpre,
                                                int* offv) {
  __shared__ int sh[256];
  const int b = blockIdx.x, t = threadIdx.x;
  const int base = b * 1024 + t * 4;
  int v[4], p[4], s = 0;
  #pragma unroll
  for (int k = 0; k < 4; ++k) {
    const int idx = base + k;
    v[k] = (idx < N_NODES) ? cnt[idx] : 0;
    p[k] = s; s += v[k];
  }
  sh[t] = s; __syncthreads();
  const int tot = s;
  for (int o = 1; o < 256; o <<= 1) {
    const int tv = (t >= o) ? sh[t - o] : 0;
    __syncthreads();
    sh[t] += tv;
    __syncthreads();
  }
  const int gb = bpre[b] + (sh[t] - tot);
  #pragma unroll
  for (int k = 0; k < 4; ++k) {
    const int idx = base + k;
    if (idx < N_NODES) offv[idx] = gb + p[k];
  }
}

__global__ __launch_bounds__(256) void k_place(const int* __restrict__ ei,
                                               const int* __restrict__ offv,
                                               const int* __restrict__ slot,
                                               int* perm) {
  const int e = blockIdx.x * 256 + threadIdx.x;
  if (e < N_EDGES) perm[offv[ei[N_EDGES + e]] + slot[e]] = e;
}

// ===========================================================================
// K1: edge GEMM  msg[e] = bf16([x[row], edge_attr] @ W1 + b1)  (no atomics)
// ===========================================================================
#define EBM 128
#define EK  160
#define ELD 168

__global__ __launch_bounds__(256) void k_edge2(
    const float* __restrict__ x, const int* __restrict__ ei,
    const float* __restrict__ ea, const float* __restrict__ W1,
    const float* __restrict__ b1, short* __restrict__ msg)
{
  __shared__ short lA[EBM * ELD];
  __shared__ short lB[HIDDEN * ELD];
  const int tid = threadIdx.x;
  const int e0  = blockIdx.x * EBM;

  for (int i = tid; i < (EK * HIDDEN) / 4; i += 256) {
    const int k = i >> 5;
    const int n = (i & 31) << 2;
    const float4 v = *(const float4*)&W1[k * HIDDEN + n];
    lB[(n + 0) * ELD + k] = f2b(v.x);
    lB[(n + 1) * ELD + k] = f2b(v.y);
    lB[(n + 2) * ELD + k] = f2b(v.z);
    lB[(n + 3) * ELD + k] = f2b(v.w);
  }
  for (int i = tid; i < EBM * 40; i += 256) {
    const int m = i / 40;
    const int q = i % 40;
    float4 v;
    if (q < 32) {
      const int r = ei[e0 + m];
      v = *(const float4*)&x[(size_t)r * D_NODE + (q << 2)];
    } else {
      v = *(const float4*)&ea[(size_t)(e0 + m) * D_EDGE + ((q - 32) << 2)];
    }
    short4v s = { f2b(v.x), f2b(v.y), f2b(v.z), f2b(v.w) };
    *(short4v*)&lA[m * ELD + (q << 2)] = s;
  }
  __syncthreads();

  const int lane = tid & 63;
  const int wid  = tid >> 6;
  const int wm = wid >> 1, wn = wid & 1;
  const int lrow = lane & 15;
  const int lk   = (lane >> 4) << 3;

  f32x4 acc[4][4] = {};
  #pragma unroll
  for (int kt = 0; kt < 5; ++kt) {
    const int ks = kt * 32 + lk;
    bf16x8 af[4], bfr[4];
    #pragma unroll
    for (int i = 0; i < 4; ++i)
      af[i]  = *(const bf16x8*)&lA[(wm * 64 + i * 16 + lrow) * ELD + ks];
    #pragma unroll
    for (int j = 0; j < 4; ++j)
      bfr[j] = *(const bf16x8*)&lB[(wn * 64 + j * 16 + lrow) * ELD + ks];
    #pragma unroll
    for (int i = 0; i < 4; ++i)
      #pragma unroll
      for (int j = 0; j < 4; ++j)
        acc[i][j] = __builtin_amdgcn_mfma_f32_16x16x32_bf16(af[i], bfr[j], acc[i][j], 0, 0, 0);
  }

  const int rb = wm * 64 + ((lane >> 4) << 2);
  const int cb = wn * 64 + lrow;
  #pragma unroll
  for (int j = 0; j < 4; ++j) {
    const int c = cb + j * 16;
    const float bias = b1[c];
    #pragma unroll
    for (int i = 0; i < 4; ++i) {
      #pragma unroll
      for (int r = 0; r < 4; ++r) {
        const int m = rb + i * 16 + r;
        msg[(size_t)(e0 + m) * HIDDEN + c] = f2b(acc[i][j][r] + bias);
      }
    }
  }
}

// ===========================================================================
// K2: node GEMM  out = [x, agg] @ W2 + b2, agg gathered from CSR on the fly
// ===========================================================================
#define NBM 128
#define NK  256
#define NLD 264

__global__ __launch_bounds__(256) void k_node2(
    const float* __restrict__ x, const short* __restrict__ msg,
    const int* __restrict__ offv, const int* __restrict__ cnt,
    const int* __restrict__ perm,
    const float* __restrict__ W2, const float* __restrict__ b2,
    float* __restrict__ out)
{
  __shared__ short lA[NBM * NLD];
  __shared__ short lB[HIDDEN * NLD];
  const int tid = threadIdx.x;
  const int n0  = blockIdx.x * NBM;

  for (int i = tid; i < (NK * HIDDEN) / 4; i += 256) {
    const int k = i >> 5;
    const int n = (i & 31) << 2;
    const float4 v = *(const float4*)&W2[k * HIDDEN + n];
    lB[(n + 0) * NLD + k] = f2b(v.x);
    lB[(n + 1) * NLD + k] = f2b(v.y);
    lB[(n + 2) * NLD + k] = f2b(v.z);
    lB[(n + 3) * NLD + k] = f2b(v.w);
  }
  // x half of A
  for (int i = tid; i < NBM * 32; i += 256) {
    const int m = i >> 5, q = i & 31;
    int node = n0 + m;
    if (node >= N_NODES) node = N_NODES - 1;
    const float4 v = *(const float4*)&x[(size_t)node * D_NODE + (q << 2)];
    short4v s = { f2b(v.x), f2b(v.y), f2b(v.z), f2b(v.w) };
    *(short4v*)&lA[m * NLD + (q << 2)] = s;
  }
  // agg half of A: per (node, 4 columns) sum the node's CSR run of msg rows
  for (int i = tid; i < NBM * 32; i += 256) {
    const int m = i >> 5, c4 = (i & 31) << 2;
    int node = n0 + m;
    if (node >= N_NODES) node = N_NODES - 1;
    const int s0 = offv[node];
    const int s1 = s0 + cnt[node];
    float a0 = 0.f, a1 = 0.f, a2 = 0.f, a3 = 0.f;
    for (int j = s0; j < s1; ++j) {
      const int e = perm[j];
      const short4v mv = *(const short4v*)&msg[(size_t)e * HIDDEN + c4];
      a0 += b2f(mv[0]); a1 += b2f(mv[1]); a2 += b2f(mv[2]); a3 += b2f(mv[3]);
    }
    short4v s = { f2b(a0), f2b(a1), f2b(a2), f2b(a3) };
    *(short4v*)&lA[m * NLD + 128 + c4] = s;
  }
  __syncthreads();

  const int lane = tid & 63;
  const int wid  = tid >> 6;
  const int wm = wid >> 1, wn = wid & 1;
  const int lrow = lane & 15;
  const int lk   = (lane >> 4) << 3;

  f32x4 acc[4][4] = {};
  #pragma unroll
  for (int kt = 0; kt < 8; ++kt) {
    const int ks = kt * 32 + lk;
    bf16x8 af[4], bfr[4];
    #pragma unroll
    for (int i = 0; i < 4; ++i)
      af[i]  = *(const bf16x8*)&lA[(wm * 64 + i * 16 + lrow) * NLD + ks];
    #pragma unroll
    for (int j = 0; j < 4; ++j)
      bfr[j] = *(const bf16x8*)&lB[(wn * 64 + j * 16 + lrow) * NLD + ks];
    #pragma unroll
    for (int i = 0; i < 4; ++i)
      #pragma unroll
      for (int j = 0; j < 4; ++j)
        acc[i][j] = __builtin_amdgcn_mfma_f32_16x16x32_bf16(af[i], bfr[j], acc[i][j], 0, 0, 0);
  }

  const int rb = wm * 64 + ((lane >> 4) << 2);
  const int cb = wn * 64 + lrow;
  #pragma unroll
  for (int j = 0; j < 4; ++j) {
    const int c = cb + j * 16;
    const float bias = b2[c];
    #pragma unroll
    for (int i = 0; i < 4; ++i) {
      #pragma unroll
      for (int r = 0; r < 4; ++r) {
        const int m = rb + i * 16 + r;
        const int node = n0 + m;
        if (node < N_NODES)
          out[(size_t)node * HIDDEN + c] = acc[i][j][r] + bias;
      }
    }
  }
}

// ===========================================================================
// Fallback path (round-1): atomic scatter into d_out-as-agg
// ===========================================================================
__global__ __launch_bounds__(256) void k_edge(
    const float* __restrict__ x, const int* __restrict__ ei,
    const float* __restrict__ ea, const float* __restrict__ W1,
    const float* __restrict__ b1, float* agg)
{
  __shared__ short lA[EBM * ELD];
  __shared__ short lB[HIDDEN * ELD];
  const int tid = threadIdx.x;
  const int e0  = blockIdx.x * EBM;

  for (int i = tid; i < (EK * HIDDEN) / 4; i += 256) {
    const int k = i >> 5;
    const int n = (i & 31) << 2;
    const float4 v = *(const float4*)&W1[k * HIDDEN + n];
    lB[(n + 0) * ELD + k] = f2b(v.x);
    lB[(n + 1) * ELD + k] = f2b(v.y);
    lB[(n + 2) * ELD + k] = f2b(v.z);
    lB[(n + 3) * ELD + k] = f2b(v.w);
  }
  for (int i = tid; i < EBM * 40; i += 256) {
    const int m = i / 40;
    const int q = i % 40;
    float4 v;
    if (q < 32) {
      const int r = ei[e0 + m];
      v = *(const float4*)&x[(size_t)r * D_NODE + (q << 2)];
    } else {
      v = *(const float4*)&ea[(size_t)(e0 + m) * D_EDGE + ((q - 32) << 2)];
    }
    short4v s = { f2b(v.x), f2b(v.y), f2b(v.z), f2b(v.w) };
    *(short4v*)&lA[m * ELD + (q << 2)] = s;
  }
  __syncthreads();

  const int lane = tid & 63;
  const int wid  = tid >> 6;
  const int wm = wid >> 1, wn = wid & 1;
  const int lrow = lane & 15;
  const int lk   = (lane >> 4) << 3;

  f32x4 acc[4][4] = {};
  #pragma unroll
  for (int kt = 0; kt < 5; ++kt) {
    const int ks = kt * 32 + lk;
    bf16x8 af[4], bfr[4];
    #pragma unroll
    for (int i = 0; i < 4; ++i)
      af[i]  = *(const bf16x8*)&lA[(wm * 64 + i * 16 + lrow) * ELD + ks];
    #pragma unroll
    for (int j = 0; j < 4; ++j)
      bfr[j] = *(const bf16x8*)&lB[(wn * 64 + j * 16 + lrow) * ELD + ks];
    #pragma unroll
    for (int i = 0; i < 4; ++i)
      #pragma unroll
      for (int j = 0; j < 4; ++j)
        acc[i][j] = __builtin_amdgcn_mfma_f32_16x16x32_bf16(af[i], bfr[j], acc[i][j], 0, 0, 0);
  }

  const int rb = wm * 64 + ((lane >> 4) << 2);
  const int cb = wn * 64 + lrow;
  #pragma unroll
  for (int j = 0; j < 4; ++j) {
    const int c = cb + j * 16;
    const float bias = b1[c];
    #pragma unroll
    for (int i = 0; i < 4; ++i) {
      #pragma unroll
      for (int r = 0; r < 4; ++r) {
        const int m    = rb + i * 16 + r;
        const int node = ei[N_EDGES + e0 + m];
        unsafeAtomicAdd(&agg[(size_t)node * HIDDEN + c], acc[i][j][r] + bias);
      }
    }
  }
}

__global__ __launch_bounds__(256) void k_node(
    const float* __restrict__ x, const float* agg,
    const float* __restrict__ W2, const float* __restrict__ b2,
    float* out)
{
  __shared__ short lA[NBM * NLD];
  __shared__ short lB[HIDDEN * NLD];
  const int tid = threadIdx.x;
  const int n0  = blockIdx.x * NBM;

  for (int i = tid; i < (NK * HIDDEN) / 4; i += 256) {
    const int k = i >> 5;
    const int n = (i & 31) << 2;
    const float4 v = *(const float4*)&W2[k * HIDDEN + n];
    lB[(n + 0) * NLD + k] = f2b(v.x);
    lB[(n + 1) * NLD + k] = f2b(v.y);
    lB[(n + 2) * NLD + k] = f2b(v.z);
    lB[(n + 3) * NLD + k] = f2b(v.w);
  }
  for (int i = tid; i < NBM * 64; i += 256) {
    const int m = i >> 6, q = i & 63;
    int node = n0 + m;
    if (node >= N_NODES) node = N_NODES - 1;
    const float* src = (q < 32) ? &x[(size_t)node * D_NODE + (q << 2)]
                                : &agg[(size_t)node * HIDDEN + ((q - 32) << 2)];
    const float4 v = *(const float4*)src;
    short4v s = { f2b(v.x), f2b(v.y), f2b(v.z), f2b(v.w) };
    *(short4v*)&lA[m * NLD + (q << 2)] = s;
  }
  __syncthreads();

  const int lane = tid & 63;
  const int wid  = tid >> 6;
  const int wm = wid >> 1, wn = wid & 1;
  const int lrow = lane & 15;
  const int lk   = (lane >> 4) << 3;

  f32x4 acc[4][4] = {};
  #pragma unroll
  for (int kt = 0; kt < 8; ++kt) {
    const int ks = kt * 32 + lk;
    bf16x8 af[4], bfr[4];
    #pragma unroll
    for (int i = 0; i < 4; ++i)
      af[i]  = *(const bf16x8*)&lA[(wm * 64 + i * 16 + lrow) * NLD + ks];
    #pragma unroll
    for (int j = 0; j < 4; ++j)
      bfr[j] = *(const bf16x8*)&lB[(wn * 64 + j * 16 + lrow) * NLD + ks];
    #pragma unroll
    for (int i = 0; i < 4; ++i)
      #pragma unroll
      for (int j = 0; j < 4; ++j)
        acc[i][j] = __builtin_amdgcn_mfma_f32_16x16x32_bf16(af[i], bfr[j], acc[i][j], 0, 0, 0);
  }

  const int rb = wm * 64 + ((lane >> 4) << 2);
  const int cb = wn * 64 + lrow;
  #pragma unroll
  for (int j = 0; j < 4; ++j) {
    const int c = cb + j * 16;
    const float bias = b2[c];
    #pragma unroll
    for (int i = 0; i < 4; ++i) {
      #pragma unroll
      for (int r = 0; r < 4; ++r) {
        const int m    = rb + i * 16 + r;
        const int node = n0 + m;
        if (node < N_NODES)
          out[(size_t)node * HIDDEN + c] = acc[i][j][r] + bias;
      }
    }
  }
}

extern "C" void kernel_launch(void* const* d_in, const int* in_sizes, int n_in,
                              void* d_out, int out_size, void* d_ws, size_t ws_size,
                              hipStream_t stream) {
  const float* x  = (const float*)d_in[0];
  const int*   ei = (const int*)d_in[1];
  const float* ea = (const float*)d_in[2];
  const float* W1 = (const float*)d_in[5];
  const float* b1 = (const float*)d_in[6];
  const float* W2 = (const float*)d_in[7];
  const float* b2 = (const float*)d_in[8];
  float* out = (float*)d_out;

  const size_t MSG_B  = (size_t)N_EDGES * HIDDEN * 2;  // 163,840,000
  const size_t CNT_B  = (size_t)N_NODES * 4;           //     800,000
  const size_t SLOT_B = (size_t)N_EDGES * 4;           //   2,560,000
  const size_t o_msg  = 0;
  const size_t o_cnt  = o_msg + MSG_B;
  const size_t o_off  = o_cnt + CNT_B;
  const size_t o_slot = o_off + CNT_B;
  const size_t o_perm = o_slot + SLOT_B;
  const size_t o_bsum = o_perm + SLOT_B;
  const size_t o_bpre = o_bsum + 1024;
  const size_t need   = o_bpre + 1024;

  if (ws_size >= need) {
    short* msg  = (short*)((char*)d_ws + o_msg);
    int*   cnt  = (int*)((char*)d_ws + o_cnt);
    int*   offv = (int*)((char*)d_ws + o_off);
    int*   slot = (int*)((char*)d_ws + o_slot);
    int*   perm = (int*)((char*)d_ws + o_perm);
    int*   bsum = (int*)((char*)d_ws + o_bsum);
    int*   bpre = (int*)((char*)d_ws + o_bpre);

    hipMemsetAsync(cnt, 0, CNT_B, stream);
    k_hist <<<(N_EDGES + 255) / 256, 256, 0, stream>>>(ei, cnt, slot);
    k_scan_a<<<SCAN_NB, 256, 0, stream>>>(cnt, bsum);
    k_scan_b<<<1, 256, 0, stream>>>(bsum, bpre);
    k_scan_c<<<SCAN_NB, 256, 0, stream>>>(cnt, bpre, offv);
    k_place<<<(N_EDGES + 255) / 256, 256, 0, stream>>>(ei, offv, slot, perm);
    k_edge2<<<N_EDGES / EBM, 256, 0, stream>>>(x, ei, ea, W1, b1, msg);
    k_node2<<<(N_NODES + NBM - 1) / NBM, 256, 0, stream>>>(x, msg, offv, cnt, perm, W2, b2, out);
  } else {
    hipMemsetAsync(out, 0, (size_t)N_NODES * HIDDEN * sizeof(float), stream);
    k_edge<<<N_EDGES / EBM, 256, 0, stream>>>(x, ei, ea, W1, b1, out);
    k_node<<<(N_NODES + NBM - 1) / NBM, 256, 0, stream>>>(x, out, W2, b2, out);
  }
}

// Round 3
// 479.014 us; speedup vs baseline: 2.3560x; 2.3560x over previous
//
#include <hip/hip_runtime.h>
#include <hip/hip_bf16.h>

#define N_NODES 200000
#define N_EDGES 640000
#define D_NODE 128
#define D_EDGE 32
#define HIDDEN 128

using bf16x8  = __attribute__((ext_vector_type(8))) short;
using f32x4   = __attribute__((ext_vector_type(4))) float;
using short4v = __attribute__((ext_vector_type(4))) short;

__device__ __forceinline__ short f2b(float f) {
  return __builtin_bit_cast(short, __float2bfloat16(f));
}
__device__ __forceinline__ float b2f(short s) {
  unsigned u = ((unsigned)(unsigned short)s) << 16;
  return __builtin_bit_cast(float, u);
}

// ===========================================================================
// Prep: x -> bf16 (plan A), W1/W2 -> bf16 transposed [n][k]
// ===========================================================================
__global__ __launch_bounds__(256) void k_prep_x(const float* __restrict__ x,
                                                short* __restrict__ xb) {
  const int i = blockIdx.x * 256 + threadIdx.x;   // 6.4M float4
  const float4 v = *(const float4*)&x[(size_t)i * 4];
  short4v s = { f2b(v.x), f2b(v.y), f2b(v.z), f2b(v.w) };
  *(short4v*)&xb[(size_t)i * 4] = s;
}

__global__ __launch_bounds__(256) void k_prep_w(const float* __restrict__ W1,
                                                const float* __restrict__ W2,
                                                short* __restrict__ W1bT,
                                                short* __restrict__ W2bT) {
  const int tid = threadIdx.x;
  for (int i = tid; i < 160 * 128; i += 256) {
    const int k = i >> 7, n = i & 127;
    W1bT[n * 160 + k] = f2b(W1[i]);
  }
  for (int i = tid; i < 256 * 128; i += 256) {
    const int k = i >> 7, n = i & 127;
    W2bT[n * 256 + k] = f2b(W2[i]);
  }
}

// ===========================================================================
// CSR build: hist -> scan(3) -> place
// ===========================================================================
__global__ __launch_bounds__(256) void k_hist(const int* __restrict__ ei,
                                              int* cnt, int* slot) {
  const int e = blockIdx.x * 256 + threadIdx.x;
  if (e < N_EDGES) slot[e] = atomicAdd(&cnt[ei[N_EDGES + e]], 1);
}

#define SCAN_NB 196  // ceil(200000/1024)

__global__ __launch_bounds__(256) void k_scan_a(const int* __restrict__ cnt,
                                                int* bsum) {
  __shared__ int sh[256];
  const int b = blockIdx.x, t = threadIdx.x;
  const int base = b * 1024 + t * 4;
  int s = 0;
  #pragma unroll
  for (int k = 0; k < 4; ++k) {
    const int idx = base + k;
    s += (idx < N_NODES) ? cnt[idx] : 0;
  }
  sh[t] = s; __syncthreads();
  for (int o = 128; o > 0; o >>= 1) {
    if (t < o) sh[t] += sh[t + o];
    __syncthreads();
  }
  if (t == 0) bsum[b] = sh[0];
}

__global__ __launch_bounds__(256) void k_scan_b(const int* __restrict__ bsum,
                                                int* bpre) {
  __shared__ int sh[256];
  const int t = threadIdx.x;
  const int v0 = (t < SCAN_NB) ? bsum[t] : 0;
  sh[t] = v0; __syncthreads();
  for (int o = 1; o < 256; o <<= 1) {
    const int tv = (t >= o) ? sh[t - o] : 0;
    __syncthreads();
    sh[t] += tv;
    __syncthreads();
  }
  bpre[t] = sh[t] - v0;  // exclusive
}

__global__ __launch_bounds__(256) void k_scan_c(const int* __restrict__ cnt,
                                                const int* __restrict__ bpre,
                                                int* offv) {
  __shared__ int sh[256];
  const int b = blockIdx.x, t = threadIdx.x;
  const int base = b * 1024 + t * 4;
  int v[4], p[4], s = 0;
  #pragma unroll
  for (int k = 0; k < 4; ++k) {
    const int idx = base + k;
    v[k] = (idx < N_NODES) ? cnt[idx] : 0;
    p[k] = s; s += v[k];
  }
  sh[t] = s; __syncthreads();
  const int tot = s;
  for (int o = 1; o < 256; o <<= 1) {
    const int tv = (t >= o) ? sh[t - o] : 0;
    __syncthreads();
    sh[t] += tv;
    __syncthreads();
  }
  const int gb = bpre[b] + (sh[t] - tot);
  #pragma unroll
  for (int k = 0; k < 4; ++k) {
    const int idx = base + k;
    if (idx < N_NODES) offv[idx] = gb + p[k];
  }
}

__global__ __launch_bounds__(256) void k_place(const int* __restrict__ ei,
                                               const int* __restrict__ offv,
                                               const int* __restrict__ slot,
                                               int* perm) {
  const int e = blockIdx.x * 256 + threadIdx.x;
  if (e < N_EDGES) perm[offv[ei[N_EDGES + e]] + slot[e]] = e;
}

// ===========================================================================
// K1: edge GEMM in sorted order.  msg_sorted[j] = bf16(cat(x[row[perm[j]]],
//     ea[perm[j]]) @ W1 + b1).  Two K-phases reuse 70KB LDS -> 2 blocks/CU.
// ===========================================================================
#define LD2 136   // stride 272B = 68dw = 4 mod 32 -> 2-way bank alias (free)

__global__ __launch_bounds__(256) void k_edge3(
    const float* __restrict__ x, const short* __restrict__ xb,
    const int* __restrict__ ei, const int* __restrict__ perm,
    const float* __restrict__ ea,
    const short* __restrict__ W1bT, const float* __restrict__ b1,
    short* __restrict__ msg)
{
  __shared__ short lA[128 * LD2];   // 34816 B
  __shared__ short lB[128 * LD2];   // 34816 B
  const int tid = threadIdx.x;
  const int e0  = blockIdx.x * 128;

  // ---- phase 1: K = 0..127 (source-node features) ----
  for (int i = tid; i < 2048; i += 256) {
    const int n = i >> 4, c = (i & 15) << 3;
    *(bf16x8*)&lB[n * LD2 + c] = *(const bf16x8*)&W1bT[n * 160 + c];
  }
  for (int i = tid; i < 2048; i += 256) {
    const int m = i >> 4, c = (i & 15) << 3;
    const int e   = perm[e0 + m];
    const int src = ei[e];                      // source node
    if (xb) {
      *(bf16x8*)&lA[m * LD2 + c] = *(const bf16x8*)&xb[(size_t)src * 128 + c];
    } else {
      const float4 v0 = *(const float4*)&x[(size_t)src * 128 + c];
      const float4 v1 = *(const float4*)&x[(size_t)src * 128 + c + 4];
      short4v s0 = { f2b(v0.x), f2b(v0.y), f2b(v0.z), f2b(v0.w) };
      short4v s1 = { f2b(v1.x), f2b(v1.y), f2b(v1.z), f2b(v1.w) };
      *(short4v*)&lA[m * LD2 + c]     = s0;
      *(short4v*)&lA[m * LD2 + c + 4] = s1;
    }
  }
  __syncthreads();

  const int lane = tid & 63;
  const int wid  = tid >> 6;
  const int wm = wid >> 1, wn = wid & 1;
  const int lrow = lane & 15;
  const int lk   = (lane >> 4) << 3;

  f32x4 acc[4][4] = {};
  #pragma unroll
  for (int kt = 0; kt < 4; ++kt) {
    const int ks = kt * 32 + lk;
    bf16x8 af[4], bfr[4];
    #pragma unroll
    for (int i = 0; i < 4; ++i)
      af[i]  = *(const bf16x8*)&lA[(wm * 64 + i * 16 + lrow) * LD2 + ks];
    #pragma unroll
    for (int j = 0; j < 4; ++j)
      bfr[j] = *(const bf16x8*)&lB[(wn * 64 + j * 16 + lrow) * LD2 + ks];
    #pragma unroll
    for (int i = 0; i < 4; ++i)
      #pragma unroll
      for (int j = 0; j < 4; ++j)
        acc[i][j] = __builtin_amdgcn_mfma_f32_16x16x32_bf16(af[i], bfr[j], acc[i][j], 0, 0, 0);
  }
  __syncthreads();

  // ---- phase 2: K = 128..159 (edge features) ----
  for (int i = tid; i < 512; i += 256) {
    const int n = i >> 2, c = (i & 3) << 3;
    *(bf16x8*)&lB[n * LD2 + c] = *(const bf16x8*)&W1bT[n * 160 + 128 + c];
  }
  for (int i = tid; i < 512; i += 256) {
    const int m = i >> 2, c = (i & 3) << 3;
    const int e = perm[e0 + m];
    const float4 v0 = *(const float4*)&ea[(size_t)e * 32 + c];
    const float4 v1 = *(const float4*)&ea[(size_t)e * 32 + c + 4];
    short4v s0 = { f2b(v0.x), f2b(v0.y), f2b(v0.z), f2b(v0.w) };
    short4v s1 = { f2b(v1.x), f2b(v1.y), f2b(v1.z), f2b(v1.w) };
    *(short4v*)&lA[m * LD2 + c]     = s0;
    *(short4v*)&lA[m * LD2 + c + 4] = s1;
  }
  __syncthreads();

  {
    bf16x8 af[4], bfr[4];
    #pragma unroll
    for (int i = 0; i < 4; ++i)
      af[i]  = *(const bf16x8*)&lA[(wm * 64 + i * 16 + lrow) * LD2 + lk];
    #pragma unroll
    for (int j = 0; j < 4; ++j)
      bfr[j] = *(const bf16x8*)&lB[(wn * 64 + j * 16 + lrow) * LD2 + lk];
    #pragma unroll
    for (int i = 0; i < 4; ++i)
      #pragma unroll
      for (int j = 0; j < 4; ++j)
        acc[i][j] = __builtin_amdgcn_mfma_f32_16x16x32_bf16(af[i], bfr[j], acc[i][j], 0, 0, 0);
  }

  // ---- epilogue: coalesced write to msg_sorted ----
  const int rb = wm * 64 + ((lane >> 4) << 2);
  const int cb = wn * 64 + lrow;
  #pragma unroll
  for (int j = 0; j < 4; ++j) {
    const int c = cb + j * 16;
    const float bias = b1[c];
    #pragma unroll
    for (int i = 0; i < 4; ++i) {
      #pragma unroll
      for (int r = 0; r < 4; ++r) {
        const int m = rb + i * 16 + r;
        msg[(size_t)(e0 + m) * HIDDEN + c] = f2b(acc[i][j][r] + bias);
      }
    }
  }
}

// ===========================================================================
// K2: aggregation.  agg[n] = sum of contiguous msg_sorted run.  Sequential
//     coalesced reads, no LDS, high occupancy -> latency hidden by TLP.
// ===========================================================================
__global__ __launch_bounds__(256) void k_agg(
    const short* __restrict__ msg, const int* __restrict__ offv,
    const int* __restrict__ cnt, float* __restrict__ agg)
{
  const int gtid = blockIdx.x * 256 + threadIdx.x;
  const int node = gtid >> 5;
  const int c4   = (gtid & 31) << 2;
  if (node >= N_NODES) return;
  const int s0 = offv[node];
  const int s1 = s0 + cnt[node];
  float a0 = 0.f, a1 = 0.f, a2 = 0.f, a3 = 0.f;
  for (int j = s0; j < s1; ++j) {
    const short4v mv = *(const short4v*)&msg[(size_t)j * HIDDEN + c4];
    a0 += b2f(mv[0]); a1 += b2f(mv[1]); a2 += b2f(mv[2]); a3 += b2f(mv[3]);
  }
  float4 o; o.x = a0; o.y = a1; o.z = a2; o.w = a3;
  *(float4*)&agg[(size_t)node * HIDDEN + c4] = o;
}

// ===========================================================================
// K3: node GEMM  out = [x, agg] @ W2 + b2.  Two K-phases, 70KB LDS,
//     2 blocks/CU.  agg aliases out (d_out): block-local RAW only -> safe.
// ===========================================================================
__global__ __launch_bounds__(256) void k_node3(
    const float* __restrict__ x, const short* __restrict__ xb,
    const float* agg, const short* __restrict__ W2bT,
    const float* __restrict__ b2, float* out)
{
  __shared__ short lA[128 * LD2];
  __shared__ short lB[128 * LD2];
  const int tid = threadIdx.x;
  const int n0  = blockIdx.x * 128;

  // ---- phase 1: K = 0..127 (x) ----
  for (int i = tid; i < 2048; i += 256) {
    const int n = i >> 4, c = (i & 15) << 3;
    *(bf16x8*)&lB[n * LD2 + c] = *(const bf16x8*)&W2bT[n * 256 + c];
  }
  for (int i = tid; i < 2048; i += 256) {
    const int m = i >> 4, c = (i & 15) << 3;
    int node = n0 + m;
    if (node >= N_NODES) node = N_NODES - 1;
    if (xb) {
      *(bf16x8*)&lA[m * LD2 + c] = *(const bf16x8*)&xb[(size_t)node * 128 + c];
    } else {
      const float4 v0 = *(const float4*)&x[(size_t)node * 128 + c];
      const float4 v1 = *(const float4*)&x[(size_t)node * 128 + c + 4];
      short4v s0 = { f2b(v0.x), f2b(v0.y), f2b(v0.z), f2b(v0.w) };
      short4v s1 = { f2b(v1.x), f2b(v1.y), f2b(v1.z), f2b(v1.w) };
      *(short4v*)&lA[m * LD2 + c]     = s0;
      *(short4v*)&lA[m * LD2 + c + 4] = s1;
    }
  }
  __syncthreads();

  const int lane = tid & 63;
  const int wid  = tid >> 6;
  const int wm = wid >> 1, wn = wid & 1;
  const int lrow = lane & 15;
  const int lk   = (lane >> 4) << 3;

  f32x4 acc[4][4] = {};
  #pragma unroll
  for (int kt = 0; kt < 4; ++kt) {
    const int ks = kt * 32 + lk;
    bf16x8 af[4], bfr[4];
    #pragma unroll
    for (int i = 0; i < 4; ++i)
      af[i]  = *(const bf16x8*)&lA[(wm * 64 + i * 16 + lrow) * LD2 + ks];
    #pragma unroll
    for (int j = 0; j < 4; ++j)
      bfr[j] = *(const bf16x8*)&lB[(wn * 64 + j * 16 + lrow) * LD2 + ks];
    #pragma unroll
    for (int i = 0; i < 4; ++i)
      #pragma unroll
      for (int j = 0; j < 4; ++j)
        acc[i][j] = __builtin_amdgcn_mfma_f32_16x16x32_bf16(af[i], bfr[j], acc[i][j], 0, 0, 0);
  }
  __syncthreads();

  // ---- phase 2: K = 128..255 (agg, f32 from d_out) ----
  for (int i = tid; i < 2048; i += 256) {
    const int n = i >> 4, c = (i & 15) << 3;
    *(bf16x8*)&lB[n * LD2 + c] = *(const bf16x8*)&W2bT[n * 256 + 128 + c];
  }
  for (int i = tid; i < 2048; i += 256) {
    const int m = i >> 4, c = (i & 15) << 3;
    int node = n0 + m;
    if (node >= N_NODES) node = N_NODES - 1;
    const float4 v0 = *(const float4*)&agg[(size_t)node * 128 + c];
    const float4 v1 = *(const float4*)&agg[(size_t)node * 128 + c + 4];
    short4v s0 = { f2b(v0.x), f2b(v0.y), f2b(v0.z), f2b(v0.w) };
    short4v s1 = { f2b(v1.x), f2b(v1.y), f2b(v1.z), f2b(v1.w) };
    *(short4v*)&lA[m * LD2 + c]     = s0;
    *(short4v*)&lA[m * LD2 + c + 4] = s1;
  }
  __syncthreads();

  #pragma unroll
  for (int kt = 0; kt < 4; ++kt) {
    const int ks = kt * 32 + lk;
    bf16x8 af[4], bfr[4];
    #pragma unroll
    for (int i = 0; i < 4; ++i)
      af[i]  = *(const bf16x8*)&lA[(wm * 64 + i * 16 + lrow) * LD2 + ks];
    #pragma unroll
    for (int j = 0; j < 4; ++j)
      bfr[j] = *(const bf16x8*)&lB[(wn * 64 + j * 16 + lrow) * LD2 + ks];
    #pragma unroll
    for (int i = 0; i < 4; ++i)
      #pragma unroll
      for (int j = 0; j < 4; ++j)
        acc[i][j] = __builtin_amdgcn_mfma_f32_16x16x32_bf16(af[i], bfr[j], acc[i][j], 0, 0, 0);
  }

  const int rb = wm * 64 + ((lane >> 4) << 2);
  const int cb = wn * 64 + lrow;
  #pragma unroll
  for (int j = 0; j < 4; ++j) {
    const int c = cb + j * 16;
    const float bias = b2[c];
    #pragma unroll
    for (int i = 0; i < 4; ++i) {
      #pragma unroll
      for (int r = 0; r < 4; ++r) {
        const int m = rb + i * 16 + r;
        const int node = n0 + m;
        if (node < N_NODES)
          out[(size_t)node * HIDDEN + c] = acc[i][j][r] + bias;
      }
    }
  }
}

// ===========================================================================
// Fallback path (round-1): atomic scatter into d_out-as-agg
// ===========================================================================
#define EBM 128
#define ELD 168
#define NLD 264

__global__ __launch_bounds__(256) void k_edge(
    const float* __restrict__ x, const int* __restrict__ ei,
    const float* __restrict__ ea, const float* __restrict__ W1,
    const float* __restrict__ b1, float* agg)
{
  __shared__ short lA[EBM * ELD];
  __shared__ short lB[HIDDEN * ELD];
  const int tid = threadIdx.x;
  const int e0  = blockIdx.x * EBM;

  for (int i = tid; i < (160 * HIDDEN) / 4; i += 256) {
    const int k = i >> 5;
    const int n = (i & 31) << 2;
    const float4 v = *(const float4*)&W1[k * HIDDEN + n];
    lB[(n + 0) * ELD + k] = f2b(v.x);
    lB[(n + 1) * ELD + k] = f2b(v.y);
    lB[(n + 2) * ELD + k] = f2b(v.z);
    lB[(n + 3) * ELD + k] = f2b(v.w);
  }
  for (int i = tid; i < EBM * 40; i += 256) {
    const int m = i / 40;
    const int q = i % 40;
    float4 v;
    if (q < 32) {
      const int r = ei[e0 + m];
      v = *(const float4*)&x[(size_t)r * D_NODE + (q << 2)];
    } else {
      v = *(const float4*)&ea[(size_t)(e0 + m) * D_EDGE + ((q - 32) << 2)];
    }
    short4v s = { f2b(v.x), f2b(v.y), f2b(v.z), f2b(v.w) };
    *(short4v*)&lA[m * ELD + (q << 2)] = s;
  }
  __syncthreads();

  const int lane = tid & 63;
  const int wid  = tid >> 6;
  const int wm = wid >> 1, wn = wid & 1;
  const int lrow = lane & 15;
  const int lk   = (lane >> 4) << 3;

  f32x4 acc[4][4] = {};
  #pragma unroll
  for (int kt = 0; kt < 5; ++kt) {
    const int ks = kt * 32 + lk;
    bf16x8 af[4], bfr[4];
    #pragma unroll
    for (int i = 0; i < 4; ++i)
      af[i]  = *(const bf16x8*)&lA[(wm * 64 + i * 16 + lrow) * ELD + ks];
    #pragma unroll
    for (int j = 0; j < 4; ++j)
      bfr[j] = *(const bf16x8*)&lB[(wn * 64 + j * 16 + lrow) * ELD + ks];
    #pragma unroll
    for (int i = 0; i < 4; ++i)
      #pragma unroll
      for (int j = 0; j < 4; ++j)
        acc[i][j] = __builtin_amdgcn_mfma_f32_16x16x32_bf16(af[i], bfr[j], acc[i][j], 0, 0, 0);
  }

  const int rb = wm * 64 + ((lane >> 4) << 2);
  const int cb = wn * 64 + lrow;
  #pragma unroll
  for (int j = 0; j < 4; ++j) {
    const int c = cb + j * 16;
    const float bias = b1[c];
    #pragma unroll
    for (int i = 0; i < 4; ++i) {
      #pragma unroll
      for (int r = 0; r < 4; ++r) {
        const int m    = rb + i * 16 + r;
        const int node = ei[N_EDGES + e0 + m];
        unsafeAtomicAdd(&agg[(size_t)node * HIDDEN + c], acc[i][j][r] + bias);
      }
    }
  }
}

__global__ __launch_bounds__(256) void k_node(
    const float* __restrict__ x, const float* agg,
    const float* __restrict__ W2, const float* __restrict__ b2,
    float* out)
{
  __shared__ short lA[128 * NLD];
  __shared__ short lB[HIDDEN * NLD];
  const int tid = threadIdx.x;
  const int n0  = blockIdx.x * 128;

  for (int i = tid; i < (256 * HIDDEN) / 4; i += 256) {
    const int k = i >> 5;
    const int n = (i & 31) << 2;
    const float4 v = *(const float4*)&W2[k * HIDDEN + n];
    lB[(n + 0) * NLD + k] = f2b(v.x);
    lB[(n + 1) * NLD + k] = f2b(v.y);
    lB[(n + 2) * NLD + k] = f2b(v.z);
    lB[(n + 3) * NLD + k] = f2b(v.w);
  }
  for (int i = tid; i < 128 * 64; i += 256) {
    const int m = i >> 6, q = i & 63;
    int node = n0 + m;
    if (node >= N_NODES) node = N_NODES - 1;
    const float* src = (q < 32) ? &x[(size_t)node * D_NODE + (q << 2)]
                                : &agg[(size_t)node * HIDDEN + ((q - 32) << 2)];
    const float4 v = *(const float4*)src;
    short4v s = { f2b(v.x), f2b(v.y), f2b(v.z), f2b(v.w) };
    *(short4v*)&lA[m * NLD + (q << 2)] = s;
  }
  __syncthreads();

  const int lane = tid & 63;
  const int wid  = tid >> 6;
  const int wm = wid >> 1, wn = wid & 1;
  const int lrow = lane & 15;
  const int lk   = (lane >> 4) << 3;

  f32x4 acc[4][4] = {};
  #pragma unroll
  for (int kt = 0; kt < 8; ++kt) {
    const int ks = kt * 32 + lk;
    bf16x8 af[4], bfr[4];
    #pragma unroll
    for (int i = 0; i < 4; ++i)
      af[i]  = *(const bf16x8*)&lA[(wm * 64 + i * 16 + lrow) * NLD + ks];
    #pragma unroll
    for (int j = 0; j < 4; ++j)
      bfr[j] = *(const bf16x8*)&lB[(wn * 64 + j * 16 + lrow) * NLD + ks];
    #pragma unroll
    for (int i = 0; i < 4; ++i)
      #pragma unroll
      for (int j = 0; j < 4; ++j)
        acc[i][j] = __builtin_amdgcn_mfma_f32_16x16x32_bf16(af[i], bfr[j], acc[i][j], 0, 0, 0);
  }

  const int rb = wm * 64 + ((lane >> 4) << 2);
  const int cb = wn * 64 + lrow;
  #pragma unroll
  for (int j = 0; j < 4; ++j) {
    const int c = cb + j * 16;
    const float bias = b2[c];
    #pragma unroll
    for (int i = 0; i < 4; ++i) {
      #pragma unroll
      for (int r = 0; r < 4; ++r) {
        const int m    = rb + i * 16 + r;
        const int node = n0 + m;
        if (node < N_NODES)
          out[(size_t)node * HIDDEN + c] = acc[i][j][r] + bias;
      }
    }
  }
}

extern "C" void kernel_launch(void* const* d_in, const int* in_sizes, int n_in,
                              void* d_out, int out_size, void* d_ws, size_t ws_size,
                              hipStream_t stream) {
  const float* x  = (const float*)d_in[0];
  const int*   ei = (const int*)d_in[1];
  const float* ea = (const float*)d_in[2];
  const float* W1 = (const float*)d_in[5];
  const float* b1 = (const float*)d_in[6];
  const float* W2 = (const float*)d_in[7];
  const float* b2 = (const float*)d_in[8];
  float* out = (float*)d_out;

  const size_t MSG_B  = (size_t)N_EDGES * HIDDEN * 2;   // 163,840,000
  const size_t XB_B   = (size_t)N_NODES * D_NODE * 2;   //  51,200,000
  const size_t CNT_B  = (size_t)N_NODES * 4;
  const size_t SLOT_B = (size_t)N_EDGES * 4;

  // Plan B layout (no xb):
  const size_t o_msg  = 0;
  const size_t o_w1t  = o_msg + MSG_B;
  const size_t o_w2t  = o_w1t + 128 * 160 * 2;
  const size_t o_cnt  = o_w2t + 128 * 256 * 2;
  const size_t o_off  = o_cnt + CNT_B;
  const size_t o_slot = o_off + CNT_B;
  const size_t o_perm = o_slot + SLOT_B;
  const size_t o_bsum = o_perm + SLOT_B;
  const size_t o_bpre = o_bsum + 1024;
  const size_t o_xb   = o_bpre + 1024;          // plan A extension
  const size_t need_b = o_xb;
  const size_t need_a = o_xb + XB_B;

  if (ws_size >= need_b) {
    short* msg  = (short*)((char*)d_ws + o_msg);
    short* W1bT = (short*)((char*)d_ws + o_w1t);
    short* W2bT = (short*)((char*)d_ws + o_w2t);
    int*   cnt  = (int*)((char*)d_ws + o_cnt);
    int*   offv = (int*)((char*)d_ws + o_off);
    int*   slot = (int*)((char*)d_ws + o_slot);
    int*   perm = (int*)((char*)d_ws + o_perm);
    int*   bsum = (int*)((char*)d_ws + o_bsum);
    int*   bpre = (int*)((char*)d_ws + o_bpre);
    short* xb   = (ws_size >= need_a) ? (short*)((char*)d_ws + o_xb) : (short*)nullptr;

    if (xb) k_prep_x<<<(N_NODES * D_NODE) / 1024, 256, 0, stream>>>(x, xb);
    k_prep_w<<<1, 256, 0, stream>>>(W1, W2, W1bT, W2bT);

    hipMemsetAsync(cnt, 0, CNT_B, stream);
    k_hist <<<(N_EDGES + 255) / 256, 256, 0, stream>>>(ei, cnt, slot);
    k_scan_a<<<SCAN_NB, 256, 0, stream>>>(cnt, bsum);
    k_scan_b<<<1, 256, 0, stream>>>(bsum, bpre);
    k_scan_c<<<SCAN_NB, 256, 0, stream>>>(cnt, bpre, offv);
    k_place<<<(N_EDGES + 255) / 256, 256, 0, stream>>>(ei, offv, slot, perm);

    k_edge3<<<N_EDGES / 128, 256, 0, stream>>>(x, xb, ei, perm, ea, W1bT, b1, msg);
    k_agg  <<<(N_NODES * 32 + 255) / 256, 256, 0, stream>>>(msg, offv, cnt, out);
    k_node3<<<(N_NODES + 127) / 128, 256, 0, stream>>>(x, xb, out, W2bT, b2, out);
  } else {
    hipMemsetAsync(out, 0, (size_t)N_NODES * HIDDEN * sizeof(float), stream);
    k_edge<<<N_EDGES / EBM, 256, 0, stream>>>(x, ei, ea, W1, b1, out);
    k_node<<<(N_NODES + 127) / 128, 256, 0, stream>>>(x, out, W2, b2, out);
  }
}

// Round 4
// 266.372 us; speedup vs baseline: 4.2368x; 1.7983x over previous
//
#include <hip/hip_runtime.h>
#include <hip/hip_bf16.h>

#define N_NODES 200000
#define N_EDGES 640000
#define D_NODE 128
#define D_EDGE 32
#define HIDDEN 128

using bf16x8  = __attribute__((ext_vector_type(8))) short;
using f32x4   = __attribute__((ext_vector_type(4))) float;
using short4v = __attribute__((ext_vector_type(4))) short;

__device__ __forceinline__ short f2b(float f) {
  return __builtin_bit_cast(short, __float2bfloat16(f));
}
__device__ __forceinline__ float b2f(short s) {
  unsigned u = ((unsigned)(unsigned short)s) << 16;
  return __builtin_bit_cast(float, u);
}

// ===========================================================================
// Prep: x -> bf16;  WcT[c][k] = bf16 of [W2_top ; W1 @ W2_bot]^T;  bc = b1@W2_bot
// ===========================================================================
__global__ __launch_bounds__(256) void k_prep_x(const float* __restrict__ x,
                                                short* __restrict__ xb) {
  const int i = blockIdx.x * 256 + threadIdx.x;   // N_NODES*128/4 float4s
  const float4 v = *(const float4*)&x[(size_t)i * 4];
  short4v s = { f2b(v.x), f2b(v.y), f2b(v.z), f2b(v.w) };
  *(short4v*)&xb[(size_t)i * 4] = s;
}

__global__ __launch_bounds__(128) void k_prep_wc(const float* __restrict__ W1,
                                                 const float* __restrict__ b1,
                                                 const float* __restrict__ W2,
                                                 short* __restrict__ WcT,
                                                 float* __restrict__ bc) {
  const int b = blockIdx.x;     // 0..288
  const int c = threadIdx.x;    // 0..127
  if (b < 128) {
    WcT[c * 288 + b] = f2b(W2[b * 128 + c]);          // top half: W2 rows 0..127
  } else if (b < 288) {
    const int i = b - 128;                             // W1 row i
    float acc = 0.f;
    #pragma unroll 8
    for (int q = 0; q < 128; ++q)
      acc += W1[i * 128 + q] * W2[(128 + q) * 128 + c];
    WcT[c * 288 + b] = f2b(acc);
  } else {
    float acc = 0.f;
    #pragma unroll 8
    for (int q = 0; q < 128; ++q)
      acc += b1[q] * W2[(128 + q) * 128 + c];
    bc[c] = acc;
  }
}

// ===========================================================================
// CSR build: hist -> scan(3) -> place (also resolves source row per slot)
// ===========================================================================
__global__ __launch_bounds__(256) void k_hist(const int* __restrict__ ei,
                                              int* cnt, int* slot) {
  const int e = blockIdx.x * 256 + threadIdx.x;
  if (e < N_EDGES) slot[e] = atomicAdd(&cnt[ei[N_EDGES + e]], 1);
}

#define SCAN_NB 196  // ceil(200000/1024)

__global__ __launch_bounds__(256) void k_scan_a(const int* __restrict__ cnt,
                                                int* bsum) {
  __shared__ int sh[256];
  const int b = blockIdx.x, t = threadIdx.x;
  const int base = b * 1024 + t * 4;
  int s = 0;
  #pragma unroll
  for (int k = 0; k < 4; ++k) {
    const int idx = base + k;
    s += (idx < N_NODES) ? cnt[idx] : 0;
  }
  sh[t] = s; __syncthreads();
  for (int o = 128; o > 0; o >>= 1) {
    if (t < o) sh[t] += sh[t + o];
    __syncthreads();
  }
  if (t == 0) bsum[b] = sh[0];
}

__global__ __launch_bounds__(256) void k_scan_b(const int* __restrict__ bsum,
                                                int* bpre) {
  __shared__ int sh[256];
  const int t = threadIdx.x;
  const int v0 = (t < SCAN_NB) ? bsum[t] : 0;
  sh[t] = v0; __syncthreads();
  for (int o = 1; o < 256; o <<= 1) {
    const int tv = (t >= o) ? sh[t - o] : 0;
    __syncthreads();
    sh[t] += tv;
    __syncthreads();
  }
  bpre[t] = sh[t] - v0;  // exclusive
}

__global__ __launch_bounds__(256) void k_scan_c(const int* __restrict__ cnt,
                                                const int* __restrict__ bpre,
                                                int* offv) {
  __shared__ int sh[256];
  const int b = blockIdx.x, t = threadIdx.x;
  const int base = b * 1024 + t * 4;
  int v[4], p[4], s = 0;
  #pragma unroll
  for (int k = 0; k < 4; ++k) {
    const int idx = base + k;
    v[k] = (idx < N_NODES) ? cnt[idx] : 0;
    p[k] = s; s += v[k];
  }
  sh[t] = s; __syncthreads();
  const int tot = s;
  for (int o = 1; o < 256; o <<= 1) {
    const int tv = (t >= o) ? sh[t - o] : 0;
    __syncthreads();
    sh[t] += tv;
    __syncthreads();
  }
  const int gb = bpre[b] + (sh[t] - tot);
  #pragma unroll
  for (int k = 0; k < 4; ++k) {
    const int idx = base + k;
    if (idx < N_NODES) offv[idx] = gb + p[k];
  }
}

__global__ __launch_bounds__(256) void k_place2(const int* __restrict__ ei,
                                                const int* __restrict__ offv,
                                                const int* __restrict__ slot,
                                                int* perm, int* rows) {
  const int e = blockIdx.x * 256 + threadIdx.x;
  if (e < N_EDGES) {
    const int j = offv[ei[N_EDGES + e]] + slot[e];
    perm[j] = e;
    rows[j] = ei[e];   // pre-resolve source row -> k_saggx has 1 gather level
  }
}

// ===========================================================================
// S aggregation.  S[n][0:128) = sum of xb[row_e];  S[n][128:160) = sum of ea_e
// LDS-free, high-occupancy, latency hidden by TLP.
// ===========================================================================
__global__ __launch_bounds__(256) void k_saggx(
    const short* __restrict__ xb, const int* __restrict__ offv,
    const int* __restrict__ cnt, const int* __restrict__ rows,
    short* __restrict__ S)
{
  const int gtid = blockIdx.x * 256 + threadIdx.x;
  const int node = gtid >> 4;
  const int oct  = (gtid & 15) << 3;   // 8 bf16 dims
  if (node >= N_NODES) return;
  const int s0 = offv[node];
  const int s1 = s0 + cnt[node];
  float a[8] = {};
  for (int j = s0; j < s1; ++j) {
    const int row = rows[j];
    const bf16x8 v = *(const bf16x8*)&xb[(size_t)row * D_NODE + oct];
    #pragma unroll
    for (int k = 0; k < 8; ++k) a[k] += b2f(v[k]);
  }
  bf16x8 o;
  #pragma unroll
  for (int k = 0; k < 8; ++k) o[k] = f2b(a[k]);
  *(bf16x8*)&S[(size_t)node * 160 + oct] = o;
}

__global__ __launch_bounds__(256) void k_sagge(
    const float* __restrict__ ea, const int* __restrict__ offv,
    const int* __restrict__ cnt, const int* __restrict__ perm,
    short* __restrict__ S)
{
  const int gtid = blockIdx.x * 256 + threadIdx.x;
  const int node = gtid >> 3;
  const int q    = (gtid & 7) << 2;    // 4 f32 dims
  if (node >= N_NODES) return;
  const int s0 = offv[node];
  const int s1 = s0 + cnt[node];
  float a0 = 0.f, a1 = 0.f, a2 = 0.f, a3 = 0.f;
  for (int j = s0; j < s1; ++j) {
    const int e = perm[j];
    const float4 v = *(const float4*)&ea[(size_t)e * D_EDGE + q];
    a0 += v.x; a1 += v.y; a2 += v.z; a3 += v.w;
  }
  short4v o = { f2b(a0), f2b(a1), f2b(a2), f2b(a3) };
  *(short4v*)&S[(size_t)node * 160 + 128 + q] = o;
}

// ===========================================================================
// Fused output GEMM: out = [xb, S] @ Wc + cnt*bc + b2.   K=288 in 3 phases
// reusing 70KB LDS -> 2 blocks/CU.
// ===========================================================================
#define LD2 136   // bf16 stride: 272B rows -> 2-way bank alias only (free)

__global__ __launch_bounds__(256) void k_out(
    const short* __restrict__ xb, const short* __restrict__ S,
    const short* __restrict__ WcT, const float* __restrict__ bc,
    const float* __restrict__ b2, const int* __restrict__ cnt,
    float* __restrict__ out)
{
  __shared__ short lA[128 * LD2];   // 34816 B
  __shared__ short lB[128 * LD2];   // 34816 B
  const int tid = threadIdx.x;
  const int n0  = blockIdx.x * 128;

  const int lane = tid & 63;
  const int wid  = tid >> 6;
  const int wm = wid >> 1, wn = wid & 1;
  const int lrow = lane & 15;
  const int lk   = (lane >> 4) << 3;

  f32x4 acc[4][4] = {};

  // ---- phase 1: K = 0..127  (xb) ----
  for (int i = tid; i < 2048; i += 256) {
    const int n = i >> 4, c = (i & 15) << 3;
    *(bf16x8*)&lB[n * LD2 + c] = *(const bf16x8*)&WcT[n * 288 + c];
  }
  for (int i = tid; i < 2048; i += 256) {
    const int m = i >> 4, c = (i & 15) << 3;
    int node = n0 + m;
    if (node >= N_NODES) node = N_NODES - 1;
    *(bf16x8*)&lA[m * LD2 + c] = *(const bf16x8*)&xb[(size_t)node * D_NODE + c];
  }
  __syncthreads();
  #pragma unroll
  for (int kt = 0; kt < 4; ++kt) {
    const int ks = kt * 32 + lk;
    bf16x8 af[4], bfr[4];
    #pragma unroll
    for (int i = 0; i < 4; ++i)
      af[i]  = *(const bf16x8*)&lA[(wm * 64 + i * 16 + lrow) * LD2 + ks];
    #pragma unroll
    for (int j = 0; j < 4; ++j)
      bfr[j] = *(const bf16x8*)&lB[(wn * 64 + j * 16 + lrow) * LD2 + ks];
    #pragma unroll
    for (int i = 0; i < 4; ++i)
      #pragma unroll
      for (int j = 0; j < 4; ++j)
        acc[i][j] = __builtin_amdgcn_mfma_f32_16x16x32_bf16(af[i], bfr[j], acc[i][j], 0, 0, 0);
  }
  __syncthreads();

  // ---- phase 2: K = 128..255  (S dims 0..127) ----
  for (int i = tid; i < 2048; i += 256) {
    const int n = i >> 4, c = (i & 15) << 3;
    *(bf16x8*)&lB[n * LD2 + c] = *(const bf16x8*)&WcT[n * 288 + 128 + c];
  }
  for (int i = tid; i < 2048; i += 256) {
    const int m = i >> 4, c = (i & 15) << 3;
    int node = n0 + m;
    if (node >= N_NODES) node = N_NODES - 1;
    *(bf16x8*)&lA[m * LD2 + c] = *(const bf16x8*)&S[(size_t)node * 160 + c];
  }
  __syncthreads();
  #pragma unroll
  for (int kt = 0; kt < 4; ++kt) {
    const int ks = kt * 32 + lk;
    bf16x8 af[4], bfr[4];
    #pragma unroll
    for (int i = 0; i < 4; ++i)
      af[i]  = *(const bf16x8*)&lA[(wm * 64 + i * 16 + lrow) * LD2 + ks];
    #pragma unroll
    for (int j = 0; j < 4; ++j)
      bfr[j] = *(const bf16x8*)&lB[(wn * 64 + j * 16 + lrow) * LD2 + ks];
    #pragma unroll
    for (int i = 0; i < 4; ++i)
      #pragma unroll
      for (int j = 0; j < 4; ++j)
        acc[i][j] = __builtin_amdgcn_mfma_f32_16x16x32_bf16(af[i], bfr[j], acc[i][j], 0, 0, 0);
  }
  __syncthreads();

  // ---- phase 3: K = 256..287  (S dims 128..159) ----
  for (int i = tid; i < 512; i += 256) {
    const int n = i >> 2, c = (i & 3) << 3;
    *(bf16x8*)&lB[n * LD2 + c] = *(const bf16x8*)&WcT[n * 288 + 256 + c];
  }
  for (int i = tid; i < 512; i += 256) {
    const int m = i >> 2, c = (i & 3) << 3;
    int node = n0 + m;
    if (node >= N_NODES) node = N_NODES - 1;
    *(bf16x8*)&lA[m * LD2 + c] = *(const bf16x8*)&S[(size_t)node * 160 + 128 + c];
  }
  __syncthreads();
  {
    bf16x8 af[4], bfr[4];
    #pragma unroll
    for (int i = 0; i < 4; ++i)
      af[i]  = *(const bf16x8*)&lA[(wm * 64 + i * 16 + lrow) * LD2 + lk];
    #pragma unroll
    for (int j = 0; j < 4; ++j)
      bfr[j] = *(const bf16x8*)&lB[(wn * 64 + j * 16 + lrow) * LD2 + lk];
    #pragma unroll
    for (int i = 0; i < 4; ++i)
      #pragma unroll
      for (int j = 0; j < 4; ++j)
        acc[i][j] = __builtin_amdgcn_mfma_f32_16x16x32_bf16(af[i], bfr[j], acc[i][j], 0, 0, 0);
  }

  // ---- epilogue: + cnt*bc + b2 ----
  const int rb = wm * 64 + ((lane >> 4) << 2);
  const int cb = wn * 64 + lrow;
  #pragma unroll
  for (int j = 0; j < 4; ++j) {
    const int c = cb + j * 16;
    const float bcc = bc[c];
    const float b2c = b2[c];
    #pragma unroll
    for (int i = 0; i < 4; ++i) {
      #pragma unroll
      for (int r = 0; r < 4; ++r) {
        const int m = rb + i * 16 + r;
        const int node = n0 + m;
        if (node < N_NODES)
          out[(size_t)node * HIDDEN + c] = acc[i][j][r] + (float)cnt[node] * bcc + b2c;
      }
    }
  }
}

// ===========================================================================
// Fallback path (round-1 style): atomic scatter into d_out-as-agg
// ===========================================================================
#define EBM 128
#define ELD 168
#define NLD 264

__global__ __launch_bounds__(256) void k_edge(
    const float* __restrict__ x, const int* __restrict__ ei,
    const float* __restrict__ ea, const float* __restrict__ W1,
    const float* __restrict__ b1, float* agg)
{
  __shared__ short lA[EBM * ELD];
  __shared__ short lB[HIDDEN * ELD];
  const int tid = threadIdx.x;
  const int e0  = blockIdx.x * EBM;

  for (int i = tid; i < (160 * HIDDEN) / 4; i += 256) {
    const int k = i >> 5;
    const int n = (i & 31) << 2;
    const float4 v = *(const float4*)&W1[k * HIDDEN + n];
    lB[(n + 0) * ELD + k] = f2b(v.x);
    lB[(n + 1) * ELD + k] = f2b(v.y);
    lB[(n + 2) * ELD + k] = f2b(v.z);
    lB[(n + 3) * ELD + k] = f2b(v.w);
  }
  for (int i = tid; i < EBM * 40; i += 256) {
    const int m = i / 40;
    const int q = i % 40;
    float4 v;
    if (q < 32) {
      const int r = ei[e0 + m];
      v = *(const float4*)&x[(size_t)r * D_NODE + (q << 2)];
    } else {
      v = *(const float4*)&ea[(size_t)(e0 + m) * D_EDGE + ((q - 32) << 2)];
    }
    short4v s = { f2b(v.x), f2b(v.y), f2b(v.z), f2b(v.w) };
    *(short4v*)&lA[m * ELD + (q << 2)] = s;
  }
  __syncthreads();

  const int lane = tid & 63;
  const int wid  = tid >> 6;
  const int wm = wid >> 1, wn = wid & 1;
  const int lrow = lane & 15;
  const int lk   = (lane >> 4) << 3;

  f32x4 acc[4][4] = {};
  #pragma unroll
  for (int kt = 0; kt < 5; ++kt) {
    const int ks = kt * 32 + lk;
    bf16x8 af[4], bfr[4];
    #pragma unroll
    for (int i = 0; i < 4; ++i)
      af[i]  = *(const bf16x8*)&lA[(wm * 64 + i * 16 + lrow) * ELD + ks];
    #pragma unroll
    for (int j = 0; j < 4; ++j)
      bfr[j] = *(const bf16x8*)&lB[(wn * 64 + j * 16 + lrow) * ELD + ks];
    #pragma unroll
    for (int i = 0; i < 4; ++i)
      #pragma unroll
      for (int j = 0; j < 4; ++j)
        acc[i][j] = __builtin_amdgcn_mfma_f32_16x16x32_bf16(af[i], bfr[j], acc[i][j], 0, 0, 0);
  }

  const int rb = wm * 64 + ((lane >> 4) << 2);
  const int cb = wn * 64 + lrow;
  #pragma unroll
  for (int j = 0; j < 4; ++j) {
    const int c = cb + j * 16;
    const float bias = b1[c];
    #pragma unroll
    for (int i = 0; i < 4; ++i) {
      #pragma unroll
      for (int r = 0; r < 4; ++r) {
        const int m    = rb + i * 16 + r;
        const int node = ei[N_EDGES + e0 + m];
        unsafeAtomicAdd(&agg[(size_t)node * HIDDEN + c], acc[i][j][r] + bias);
      }
    }
  }
}

__global__ __launch_bounds__(256) void k_node(
    const float* __restrict__ x, const float* agg,
    const float* __restrict__ W2, const float* __restrict__ b2,
    float* out)
{
  __shared__ short lA[128 * NLD];
  __shared__ short lB[HIDDEN * NLD];
  const int tid = threadIdx.x;
  const int n0  = blockIdx.x * 128;

  for (int i = tid; i < (256 * HIDDEN) / 4; i += 256) {
    const int k = i >> 5;
    const int n = (i & 31) << 2;
    const float4 v = *(const float4*)&W2[k * HIDDEN + n];
    lB[(n + 0) * NLD + k] = f2b(v.x);
    lB[(n + 1) * NLD + k] = f2b(v.y);
    lB[(n + 2) * NLD + k] = f2b(v.z);
    lB[(n + 3) * NLD + k] = f2b(v.w);
  }
  for (int i = tid; i < 128 * 64; i += 256) {
    const int m = i >> 6, q = i & 63;
    int node = n0 + m;
    if (node >= N_NODES) node = N_NODES - 1;
    const float* src = (q < 32) ? &x[(size_t)node * D_NODE + (q << 2)]
                                : &agg[(size_t)node * HIDDEN + ((q - 32) << 2)];
    const float4 v = *(const float4*)src;
    short4v s = { f2b(v.x), f2b(v.y), f2b(v.z), f2b(v.w) };
    *(short4v*)&lA[m * NLD + (q << 2)] = s;
  }
  __syncthreads();

  const int lane = tid & 63;
  const int wid  = tid >> 6;
  const int wm = wid >> 1, wn = wid & 1;
  const int lrow = lane & 15;
  const int lk   = (lane >> 4) << 3;

  f32x4 acc[4][4] = {};
  #pragma unroll
  for (int kt = 0; kt < 8; ++kt) {
    const int ks = kt * 32 + lk;
    bf16x8 af[4], bfr[4];
    #pragma unroll
    for (int i = 0; i < 4; ++i)
      af[i]  = *(const bf16x8*)&lA[(wm * 64 + i * 16 + lrow) * NLD + ks];
    #pragma unroll
    for (int j = 0; j < 4; ++j)
      bfr[j] = *(const bf16x8*)&lB[(wn * 64 + j * 16 + lrow) * NLD + ks];
    #pragma unroll
    for (int i = 0; i < 4; ++i)
      #pragma unroll
      for (int j = 0; j < 4; ++j)
        acc[i][j] = __builtin_amdgcn_mfma_f32_16x16x32_bf16(af[i], bfr[j], acc[i][j], 0, 0, 0);
  }

  const int rb = wm * 64 + ((lane >> 4) << 2);
  const int cb = wn * 64 + lrow;
  #pragma unroll
  for (int j = 0; j < 4; ++j) {
    const int c = cb + j * 16;
    const float bias = b2[c];
    #pragma unroll
    for (int i = 0; i < 4; ++i) {
      #pragma unroll
      for (int r = 0; r < 4; ++r) {
        const int m    = rb + i * 16 + r;
        const int node = n0 + m;
        if (node < N_NODES)
          out[(size_t)node * HIDDEN + c] = acc[i][j][r] + bias;
      }
    }
  }
}

extern "C" void kernel_launch(void* const* d_in, const int* in_sizes, int n_in,
                              void* d_out, int out_size, void* d_ws, size_t ws_size,
                              hipStream_t stream) {
  const float* x  = (const float*)d_in[0];
  const int*   ei = (const int*)d_in[1];
  const float* ea = (const float*)d_in[2];
  const float* W1 = (const float*)d_in[5];
  const float* b1 = (const float*)d_in[6];
  const float* W2 = (const float*)d_in[7];
  const float* b2 = (const float*)d_in[8];
  float* out = (float*)d_out;

  const size_t S_B    = (size_t)N_NODES * 160 * 2;      // 64,000,000
  const size_t WCT_B  = 128 * 288 * 2;                  //     73,728
  const size_t BC_B   = 512;
  const size_t CNT_B  = (size_t)N_NODES * 4;            //    800,000
  const size_t SLOT_B = (size_t)N_EDGES * 4;            //  2,560,000
  const size_t XB_B   = (size_t)N_NODES * D_NODE * 2;   // 51,200,000

  const size_t o_S    = 0;
  const size_t o_wct  = o_S + S_B;
  const size_t o_bc   = o_wct + WCT_B;
  const size_t o_cnt  = o_bc + BC_B;
  const size_t o_off  = o_cnt + CNT_B;
  const size_t o_slot = o_off + CNT_B;
  const size_t o_perm = o_slot + SLOT_B;
  const size_t o_rows = o_perm + SLOT_B;
  const size_t o_bsum = o_rows + SLOT_B;
  const size_t o_bpre = o_bsum + 1024;
  const size_t o_xb   = o_bpre + 1024;
  const size_t need   = o_xb + XB_B;                    // ~124.6 MB

  if (ws_size >= need) {
    short* S    = (short*)((char*)d_ws + o_S);
    short* WcT  = (short*)((char*)d_ws + o_wct);
    float* bc   = (float*)((char*)d_ws + o_bc);
    int*   cnt  = (int*)((char*)d_ws + o_cnt);
    int*   offv = (int*)((char*)d_ws + o_off);
    int*   slot = (int*)((char*)d_ws + o_slot);
    int*   perm = (int*)((char*)d_ws + o_perm);
    int*   rows = (int*)((char*)d_ws + o_rows);
    int*   bsum = (int*)((char*)d_ws + o_bsum);
    int*   bpre = (int*)((char*)d_ws + o_bpre);
    short* xb   = (short*)((char*)d_ws + o_xb);

    k_prep_x<<<(N_NODES * D_NODE) / 1024, 256, 0, stream>>>(x, xb);
    k_prep_wc<<<289, 128, 0, stream>>>(W1, b1, W2, WcT, bc);

    hipMemsetAsync(cnt, 0, CNT_B, stream);
    k_hist <<<(N_EDGES + 255) / 256, 256, 0, stream>>>(ei, cnt, slot);
    k_scan_a<<<SCAN_NB, 256, 0, stream>>>(cnt, bsum);
    k_scan_b<<<1, 256, 0, stream>>>(bsum, bpre);
    k_scan_c<<<SCAN_NB, 256, 0, stream>>>(cnt, bpre, offv);
    k_place2<<<(N_EDGES + 255) / 256, 256, 0, stream>>>(ei, offv, slot, perm, rows);

    k_saggx<<<(N_NODES * 16 + 255) / 256, 256, 0, stream>>>(xb, offv, cnt, rows, S);
    k_sagge<<<(N_NODES * 8 + 255) / 256, 256, 0, stream>>>(ea, offv, cnt, perm, S);
    k_out  <<<(N_NODES + 127) / 128, 256, 0, stream>>>(xb, S, WcT, bc, b2, cnt, out);
  } else {
    hipMemsetAsync(out, 0, (size_t)N_NODES * HIDDEN * sizeof(float), stream);
    k_edge<<<N_EDGES / EBM, 256, 0, stream>>>(x, ei, ea, W1, b1, out);
    k_node<<<(N_NODES + 127) / 128, 256, 0, stream>>>(x, out, W2, b2, out);
  }
}

// Round 5
// 233.838 us; speedup vs baseline: 4.8262x; 1.1391x over previous
//
#include <hip/hip_runtime.h>
#include <hip/hip_bf16.h>

#define N_NODES 200000
#define N_EDGES 640000
#define D_NODE 128
#define D_EDGE 32
#define HIDDEN 128
#define KTOT 288          // 128 (x) + 128 (Sx) + 32 (Sea)

using bf16x8  = __attribute__((ext_vector_type(8))) short;
using f32x4   = __attribute__((ext_vector_type(4))) float;
using short4v = __attribute__((ext_vector_type(4))) short;

__device__ __forceinline__ short f2b(float f) {
  return __builtin_bit_cast(short, __float2bfloat16(f));
}
__device__ __forceinline__ float b2f(short s) {
  unsigned u = ((unsigned)(unsigned short)s) << 16;
  return __builtin_bit_cast(float, u);
}

// ===========================================================================
// Prep: AF[:,0:128] = bf16(x);  WcT[c][k] = bf16([W2_top ; W1@W2_bot]^T);
//       bc = b1 @ W2_bot
// ===========================================================================
__global__ __launch_bounds__(256) void k_prep_x(const float* __restrict__ x,
                                                short* __restrict__ AF) {
  const int i = blockIdx.x * 256 + threadIdx.x;   // N_NODES*16 threads exactly
  const int node = i >> 4;
  const int oct  = (i & 15) << 3;                 // 8 f32 -> 8 bf16
  const float4 v0 = *(const float4*)&x[(size_t)node * D_NODE + oct];
  const float4 v1 = *(const float4*)&x[(size_t)node * D_NODE + oct + 4];
  bf16x8 o = { f2b(v0.x), f2b(v0.y), f2b(v0.z), f2b(v0.w),
               f2b(v1.x), f2b(v1.y), f2b(v1.z), f2b(v1.w) };
  *(bf16x8*)&AF[(size_t)node * KTOT + oct] = o;
}

__global__ __launch_bounds__(128) void k_prep_wc(const float* __restrict__ W1,
                                                 const float* __restrict__ b1,
                                                 const float* __restrict__ W2,
                                                 short* __restrict__ WcT,
                                                 float* __restrict__ bc) {
  const int b = blockIdx.x;     // 0..288
  const int c = threadIdx.x;    // 0..127
  if (b < 128) {
    WcT[c * KTOT + b] = f2b(W2[b * 128 + c]);          // W2 top rows (x part)
  } else if (b < KTOT) {
    const int i = b - 128;                             // W1 row i
    float acc = 0.f;
    #pragma unroll 8
    for (int q = 0; q < 128; ++q)
      acc += W1[i * 128 + q] * W2[(128 + q) * 128 + c];
    WcT[c * KTOT + b] = f2b(acc);
  } else {
    float acc = 0.f;
    #pragma unroll 8
    for (int q = 0; q < 128; ++q)
      acc += b1[q] * W2[(128 + q) * 128 + c];
    bc[c] = acc;
  }
}

// ===========================================================================
// CSR build: hist -> scan(3) -> place (pre-resolves source row per slot)
// ===========================================================================
__global__ __launch_bounds__(256) void k_hist(const int* __restrict__ ei,
                                              int* cnt, int* slot) {
  const int e = blockIdx.x * 256 + threadIdx.x;
  if (e < N_EDGES) slot[e] = atomicAdd(&cnt[ei[N_EDGES + e]], 1);
}

#define SCAN_NB 196  // ceil(200000/1024)

__global__ __launch_bounds__(256) void k_scan_a(const int* __restrict__ cnt,
                                                int* bsum) {
  __shared__ int sh[256];
  const int b = blockIdx.x, t = threadIdx.x;
  const int base = b * 1024 + t * 4;
  int s = 0;
  #pragma unroll
  for (int k = 0; k < 4; ++k) {
    const int idx = base + k;
    s += (idx < N_NODES) ? cnt[idx] : 0;
  }
  sh[t] = s; __syncthreads();
  for (int o = 128; o > 0; o >>= 1) {
    if (t < o) sh[t] += sh[t + o];
    __syncthreads();
  }
  if (t == 0) bsum[b] = sh[0];
}

__global__ __launch_bounds__(256) void k_scan_b(const int* __restrict__ bsum,
                                                int* bpre) {
  __shared__ int sh[256];
  const int t = threadIdx.x;
  const int v0 = (t < SCAN_NB) ? bsum[t] : 0;
  sh[t] = v0; __syncthreads();
  for (int o = 1; o < 256; o <<= 1) {
    const int tv = (t >= o) ? sh[t - o] : 0;
    __syncthreads();
    sh[t] += tv;
    __syncthreads();
  }
  bpre[t] = sh[t] - v0;  // exclusive
}

__global__ __launch_bounds__(256) void k_scan_c(const int* __restrict__ cnt,
                                                const int* __restrict__ bpre,
                                                int* offv) {
  __shared__ int sh[256];
  const int b = blockIdx.x, t = threadIdx.x;
  const int base = b * 1024 + t * 4;
  int v[4], p[4], s = 0;
  #pragma unroll
  for (int k = 0; k < 4; ++k) {
    const int idx = base + k;
    v[k] = (idx < N_NODES) ? cnt[idx] : 0;
    p[k] = s; s += v[k];
  }
  sh[t] = s; __syncthreads();
  const int tot = s;
  for (int o = 1; o < 256; o <<= 1) {
    const int tv = (t >= o) ? sh[t - o] : 0;
    __syncthreads();
    sh[t] += tv;
    __syncthreads();
  }
  const int gb = bpre[b] + (sh[t] - tot);
  #pragma unroll
  for (int k = 0; k < 4; ++k) {
    const int idx = base + k;
    if (idx < N_NODES) offv[idx] = gb + p[k];
  }
}

__global__ __launch_bounds__(256) void k_place2(const int* __restrict__ ei,
                                                const int* __restrict__ offv,
                                                const int* __restrict__ slot,
                                                int* perm, int* rows) {
  const int e = blockIdx.x * 256 + threadIdx.x;
  if (e < N_EDGES) {
    const int j = offv[ei[N_EDGES + e]] + slot[e];
    perm[j] = e;
    rows[j] = ei[e];   // source row, pre-resolved -> 1 gather level later
  }
}

// ===========================================================================
// Fused S aggregation into AF.
//   gtid < 3.2M : AF[n][128+d] = sum over run of AF[rows[j]][d]   (x part)
//   else        : AF[n][256+q] = sum over run of ea[perm[j]][q]   (ea part)
// Column ranges are 64B-line-aligned -> no read/write interaction.
// ===========================================================================
__global__ __launch_bounds__(256) void k_sagg(
    const float* __restrict__ ea, const int* __restrict__ offv,
    const int* __restrict__ cnt, const int* __restrict__ rows,
    const int* __restrict__ perm, short* __restrict__ AF)
{
  const int gtid = blockIdx.x * 256 + threadIdx.x;
  if (gtid < N_NODES * 16) {
    const int node = gtid >> 4;
    const int oct  = (gtid & 15) << 3;
    const int s0 = offv[node];
    const int s1 = s0 + cnt[node];
    float a[8] = {};
    for (int j = s0; j < s1; ++j) {
      const int row = rows[j];
      const bf16x8 v = *(const bf16x8*)&AF[(size_t)row * KTOT + oct];
      #pragma unroll
      for (int k = 0; k < 8; ++k) a[k] += b2f(v[k]);
    }
    bf16x8 o;
    #pragma unroll
    for (int k = 0; k < 8; ++k) o[k] = f2b(a[k]);
    *(bf16x8*)&AF[(size_t)node * KTOT + 128 + oct] = o;
  } else {
    const int t2 = gtid - N_NODES * 16;
    const int node = t2 >> 3;
    const int q    = (t2 & 7) << 2;
    if (node >= N_NODES) return;
    const int s0 = offv[node];
    const int s1 = s0 + cnt[node];
    float a0 = 0.f, a1 = 0.f, a2 = 0.f, a3 = 0.f;
    for (int j = s0; j < s1; ++j) {
      const int e = perm[j];
      const float4 v = *(const float4*)&ea[(size_t)e * D_EDGE + q];
      a0 += v.x; a1 += v.y; a2 += v.z; a3 += v.w;
    }
    short4v o = { f2b(a0), f2b(a1), f2b(a2), f2b(a3) };
    *(short4v*)&AF[(size_t)node * KTOT + 256 + q] = o;
  }
}

// ===========================================================================
// Output GEMM: out = AF @ Wc + cnt*bc + b2.
//   BM=64 (grid 3125, exact), K=288 in 3x96 phases, LDS 39.9KB -> 4 blocks/CU.
//   Epilogue via LDS -> coalesced float4 row stores.
// ===========================================================================
#define LDP 104   // 96+8 bf16: 208B rows -> 2-way bank alias only (free)

__global__ __launch_bounds__(256, 4) void k_out2(
    const short* __restrict__ AF, const short* __restrict__ WcT,
    const float* __restrict__ bc, const float* __restrict__ b2,
    const int* __restrict__ cnt, float* __restrict__ out)
{
  __shared__ short smem[64 * LDP + 128 * LDP];   // 39936 B
  short* lA = smem;
  short* lB = smem + 64 * LDP;
  const int tid = threadIdx.x;
  const int n0  = blockIdx.x * 64;

  const int lane = tid & 63;
  const int wid  = tid >> 6;
  const int wm = wid >> 1, wn = wid & 1;          // 2x2 waves, 32x64 out each
  const int lrow = lane & 15;
  const int lk   = (lane >> 4) << 3;

  f32x4 acc[2][4] = {};

  #pragma unroll
  for (int p = 0; p < 3; ++p) {
    for (int i = tid; i < 1536; i += 256) {       // lB: 128 rows x 12 octs
      const int n = i / 12, ck = (i % 12) << 3;
      *(bf16x8*)&lB[n * LDP + ck] = *(const bf16x8*)&WcT[n * KTOT + p * 96 + ck];
    }
    for (int i = tid; i < 768; i += 256) {        // lA: 64 rows x 12 octs
      const int m = i / 12, ck = (i % 12) << 3;
      *(bf16x8*)&lA[m * LDP + ck] = *(const bf16x8*)&AF[(size_t)(n0 + m) * KTOT + p * 96 + ck];
    }
    __syncthreads();
    #pragma unroll
    for (int kt = 0; kt < 3; ++kt) {
      const int ks = kt * 32 + lk;
      bf16x8 af[2], bfr[4];
      #pragma unroll
      for (int i = 0; i < 2; ++i)
        af[i]  = *(const bf16x8*)&lA[(wm * 32 + i * 16 + lrow) * LDP + ks];
      #pragma unroll
      for (int j = 0; j < 4; ++j)
        bfr[j] = *(const bf16x8*)&lB[(wn * 64 + j * 16 + lrow) * LDP + ks];
      #pragma unroll
      for (int i = 0; i < 2; ++i)
        #pragma unroll
        for (int j = 0; j < 4; ++j)
          acc[i][j] = __builtin_amdgcn_mfma_f32_16x16x32_bf16(af[i], bfr[j], acc[i][j], 0, 0, 0);
    }
    __syncthreads();
  }

  // ---- epilogue: acc + cnt*bc + b2 -> LDS f32 [64][128] -> coalesced stores
  float* lf = (float*)smem;                       // 32768 B <= 39936 B
  const int rb = wm * 32 + ((lane >> 4) << 2);
  const int cb = wn * 64 + lrow;
  float bcv[4], b2v[4];
  #pragma unroll
  for (int j = 0; j < 4; ++j) {
    bcv[j] = bc[cb + j * 16];
    b2v[j] = b2[cb + j * 16];
  }
  #pragma unroll
  for (int i = 0; i < 2; ++i) {
    #pragma unroll
    for (int r = 0; r < 4; ++r) {
      const int row = rb + i * 16 + r;
      const float cf = (float)cnt[n0 + row];
      #pragma unroll
      for (int j = 0; j < 4; ++j)
        lf[row * 128 + cb + j * 16] = acc[i][j][r] + cf * bcv[j] + b2v[j];
    }
  }
  __syncthreads();
  #pragma unroll
  for (int u = 0; u < 8; ++u) {
    const int idx = tid + u * 256;                // 2048 float4s
    const int row = idx >> 5, f4 = (idx & 31) << 2;
    *(float4*)&out[(size_t)(n0 + row) * HIDDEN + f4] = *(const float4*)&lf[row * 128 + f4];
  }
}

extern "C" void kernel_launch(void* const* d_in, const int* in_sizes, int n_in,
                              void* d_out, int out_size, void* d_ws, size_t ws_size,
                              hipStream_t stream) {
  const float* x  = (const float*)d_in[0];
  const int*   ei = (const int*)d_in[1];
  const float* ea = (const float*)d_in[2];
  const float* W1 = (const float*)d_in[5];
  const float* b1 = (const float*)d_in[6];
  const float* W2 = (const float*)d_in[7];
  const float* b2 = (const float*)d_in[8];
  float* out = (float*)d_out;

  const size_t AF_B   = (size_t)N_NODES * KTOT * 2;   // 115,200,000
  const size_t WCT_B  = 128 * KTOT * 2;               //      73,728
  const size_t BC_B   = 512;
  const size_t CNT_B  = (size_t)N_NODES * 4;          //     800,000
  const size_t SLOT_B = (size_t)N_EDGES * 4;          //   2,560,000

  const size_t o_AF   = 0;
  const size_t o_wct  = o_AF + AF_B;
  const size_t o_bc   = o_wct + WCT_B;
  const size_t o_cnt  = o_bc + BC_B;
  const size_t o_off  = o_cnt + CNT_B;
  const size_t o_slot = o_off + CNT_B;
  const size_t o_perm = o_slot + SLOT_B;
  const size_t o_rows = o_perm + SLOT_B;
  const size_t o_bsum = o_rows + SLOT_B;
  const size_t o_bpre = o_bsum + 1024;
  // total ~124.2 MB -- fits (round-4 plan ran at 124.6 MB)

  short* AF   = (short*)((char*)d_ws + o_AF);
  short* WcT  = (short*)((char*)d_ws + o_wct);
  float* bc   = (float*)((char*)d_ws + o_bc);
  int*   cnt  = (int*)((char*)d_ws + o_cnt);
  int*   offv = (int*)((char*)d_ws + o_off);
  int*   slot = (int*)((char*)d_ws + o_slot);
  int*   perm = (int*)((char*)d_ws + o_perm);
  int*   rows = (int*)((char*)d_ws + o_rows);
  int*   bsum = (int*)((char*)d_ws + o_bsum);
  int*   bpre = (int*)((char*)d_ws + o_bpre);

  k_prep_x<<<(N_NODES * 16) / 256, 256, 0, stream>>>(x, AF);
  k_prep_wc<<<KTOT + 1, 128, 0, stream>>>(W1, b1, W2, WcT, bc);

  hipMemsetAsync(cnt, 0, CNT_B, stream);
  k_hist <<<(N_EDGES + 255) / 256, 256, 0, stream>>>(ei, cnt, slot);
  k_scan_a<<<SCAN_NB, 256, 0, stream>>>(cnt, bsum);
  k_scan_b<<<1, 256, 0, stream>>>(bsum, bpre);
  k_scan_c<<<SCAN_NB, 256, 0, stream>>>(cnt, bpre, offv);
  k_place2<<<(N_EDGES + 255) / 256, 256, 0, stream>>>(ei, offv, slot, perm, rows);

  k_sagg<<<(N_NODES * 24 + 255) / 256, 256, 0, stream>>>(ea, offv, cnt, rows, perm, AF);
  k_out2<<<N_NODES / 64, 256, 0, stream>>>(AF, WcT, bc, b2, cnt, out);
}